// Round 15
// baseline (258.140 us; speedup 1.0000x reference)
//
#include <hip/hip_runtime.h>
#include <hip/hip_bf16.h>
#include <math.h>

typedef __attribute__((ext_vector_type(4))) float f32x4;
typedef __attribute__((ext_vector_type(8))) short s16x8;
typedef __attribute__((ext_vector_type(4))) short s16x4;

#define S_LEN 4096
#define DMODEL 1024
#define NHEADS 16
#define DHEAD 64

__device__ __forceinline__ unsigned short f2bf(float f) {
  union { float f; unsigned int u; } x; x.f = f;
  return (unsigned short)((x.u + 0x7FFFu + ((x.u >> 16) & 1u)) >> 16);
}

__device__ __forceinline__ float fexp2(float x) {
#if __has_builtin(__builtin_amdgcn_exp2f)
  return __builtin_amdgcn_exp2f(x);
#else
  float r; asm("v_exp_f32 %0, %1" : "=v"(r) : "v"(x)); return r;
#endif
}

__device__ __forceinline__ void gload_lds16(const void* g, void* l) {
  __builtin_amdgcn_global_load_lds(
      (const __attribute__((address_space(1))) unsigned int*)g,
      (__attribute__((address_space(3))) unsigned int*)l, 16, 0, 0);
}

// ---------------------------------------------------------------------------
// mask pre-pass 1 body (r7-exact, COALESCED 64MB read): int32 mask [S][S] ->
// bits[qr][t] u64 (bit l = key t*64+l).
// ---------------------------------------------------------------------------
__device__ __forceinline__ void mask_pack_body(const int* __restrict__ mask,
                                               unsigned long long* __restrict__ bits,
                                               int qr) {
  const int wv = threadIdx.x >> 6, l = threadIdx.x & 63;
  const int* row = mask + (size_t)qr * S_LEN;
#pragma unroll
  for (int w0 = 0; w0 < 64; w0 += 4) {
    const int w = w0 + wv;
    unsigned long long b = __ballot(row[w * 64 + l] != 0);
    if (l == 0) bits[(size_t)qr * 64 + w] = b;
  }
}

__global__ __launch_bounds__(256) void mask_pack(const int* __restrict__ mask,
                                                 unsigned long long* __restrict__ bits) {
  mask_pack_body(mask, bits, blockIdx.x);
}

// ---------------------------------------------------------------------------
// mask pre-pass 2 (r7-exact, transpose on the 2MB bits array):
// lmask[qg][t][w], w=kg*4+j: bit[lane] = mask[qg*16+(lane&15)]
//                                             [t*64+kg*16+(lane>>4)*4+j]
// ---------------------------------------------------------------------------
__global__ __launch_bounds__(256) void mask_xpose(const unsigned long long* __restrict__ bits,
                                                  unsigned long long* __restrict__ lmask) {
  const int wv = blockIdx.x * 4 + (threadIdx.x >> 6);
  const int l = threadIdx.x & 63, lr = l & 15, lg4 = (l >> 4) * 4;
  const int qg = wv >> 6, t = wv & 63;
  const unsigned long long rw = bits[(size_t)(qg * 16 + lr) * 64 + t];
  unsigned long long mine = 0;
#pragma unroll
  for (int w = 0; w < 16; ++w) {
    const int sh = (w >> 2) * 16 + (w & 3) + lg4;
    unsigned long long b = __ballot(((rw >> sh) & 1ull) != 0);
    if (l == w) mine = b;
  }
  if (l < 16) lmask[((size_t)qg * 64 + t) * 16 + l] = mine;
}

// ---------------------------------------------------------------------------
// fused prep (big path, r14-exact): planes y<7 = fp32->bf16 cast,
// plane y==7 = COALESCED mask_pack (qr = blockIdx.x).
// ---------------------------------------------------------------------------
__global__ __launch_bounds__(256) void prep_fused(
    const float* __restrict__ s0, const float* __restrict__ s1, const float* __restrict__ s2,
    const float* __restrict__ s3, const float* __restrict__ s4, const float* __restrict__ s5,
    const float* __restrict__ s6, unsigned short* __restrict__ dst,
    const int* __restrict__ mask, unsigned long long* __restrict__ bits) {
  const int z = blockIdx.y;
  if (z == 7) {
    mask_pack_body(mask, bits, blockIdx.x);
    return;
  }
  const float* src = (z == 0) ? s0 : (z == 1) ? s1 : (z == 2) ? s2 :
                     (z == 3) ? s3 : (z == 4) ? s4 : (z == 5) ? s5 : s6;
  const int n = (z < 3) ? (S_LEN * DMODEL) : (DMODEL * DMODEL);
  unsigned short* d = dst + ((z < 3) ? (size_t)z * S_LEN * DMODEL
                                     : (size_t)3 * S_LEN * DMODEL + (size_t)(z - 3) * DMODEL * DMODEL);
  const int i = (blockIdx.x * 256 + threadIdx.x) * 4;
  if (i < n) {
    f32x4 v = *(const f32x4*)(src + i);
    s16x4 o;
#pragma unroll
    for (int j = 0; j < 4; ++j) o[j] = (short)f2bf(v[j]);
    *(s16x4*)(d + i) = o;
  }
}

// ---------------------------------------------------------------------------
// GEMM body (r7-exact, reg-staged, LDT=40 — measured-best: compiler hoists
// next-tile global loads above the barrier = implicit pipelining).
// ---------------------------------------------------------------------------
template<int A_BF16, int B_BF16, int OUT_MODE>
__device__ __forceinline__ void gemm_body(const void* __restrict__ Ap,
                                          const void* __restrict__ Wp,
                                          const float* __restrict__ bias,
                                          void* __restrict__ outp, float scale) {
  constexpr int K = DMODEL, N = DMODEL, M = S_LEN;
  constexpr int BM = 128, BK = 32, LDT = 40;
  __shared__ unsigned short Alds[BM * LDT];
  __shared__ unsigned short Blds[BM * LDT];
  const int tid = threadIdx.x;
  const int l = tid & 63, wid = tid >> 6;
  const int lr = l & 15, lg = l >> 4;
  const int bm = blockIdx.x * BM;
  const int bn = blockIdx.y * BM;
  const int wm = (wid >> 1) * 64, wn = (wid & 1) * 64;

  f32x4 acc[4][4] = {};

  for (int k0 = 0; k0 < K; k0 += BK) {
    __syncthreads();
    if constexpr (A_BF16) {
      const unsigned short* A = (const unsigned short*)Ap;
      const int col = (tid & 3) * 8, row = tid >> 2;
#pragma unroll
      for (int p = 0; p < 2; ++p) {
        const int r = row + p * 64;
        *(s16x8*)&Alds[r * LDT + col] =
            *(const s16x8*)(A + (size_t)(bm + r) * K + k0 + col);
      }
    } else {
      const float* A = (const float*)Ap;
      const int col = (tid & 7) * 4, row = tid >> 3;
#pragma unroll
      for (int p = 0; p < 4; ++p) {
        const int r = row + p * 32;
        f32x4 vv = *(const f32x4*)(A + (size_t)(bm + r) * K + k0 + col);
        s16x4 o;
#pragma unroll
        for (int j = 0; j < 4; ++j) o[j] = (short)f2bf(vv[j]);
        *(s16x4*)&Alds[r * LDT + col] = o;
      }
    }
    if constexpr (B_BF16) {
      const unsigned short* W = (const unsigned short*)Wp;
      const int col = (tid & 3) * 8, row = tid >> 2;
#pragma unroll
      for (int p = 0; p < 2; ++p) {
        const int r = row + p * 64;
        *(s16x8*)&Blds[r * LDT + col] =
            *(const s16x8*)(W + (size_t)(bn + r) * K + k0 + col);
      }
    } else {
      const float* W = (const float*)Wp;
      const int col = (tid & 7) * 4, row = tid >> 3;
#pragma unroll
      for (int p = 0; p < 4; ++p) {
        const int r = row + p * 32;
        f32x4 vv = *(const f32x4*)(W + (size_t)(bn + r) * K + k0 + col);
        s16x4 o;
#pragma unroll
        for (int j = 0; j < 4; ++j) o[j] = (short)f2bf(vv[j]);
        *(s16x4*)&Blds[r * LDT + col] = o;
      }
    }
    __syncthreads();
    s16x8 af[4], bfr[4];
#pragma unroll
    for (int mi = 0; mi < 4; ++mi)
      af[mi] = *(const s16x8*)&Alds[(wm + mi * 16 + lr) * LDT + lg * 8];
#pragma unroll
    for (int ni = 0; ni < 4; ++ni)
      bfr[ni] = *(const s16x8*)&Blds[(wn + ni * 16 + lr) * LDT + lg * 8];
#pragma unroll
    for (int mi = 0; mi < 4; ++mi)
#pragma unroll
      for (int ni = 0; ni < 4; ++ni)
        acc[mi][ni] = __builtin_amdgcn_mfma_f32_16x16x32_bf16(af[mi], bfr[ni], acc[mi][ni], 0, 0, 0);
  }

#pragma unroll
  for (int ni = 0; ni < 4; ++ni) {
    const int n = bn + wn + ni * 16 + lr;
    const float bv = bias[n];
#pragma unroll
    for (int mi = 0; mi < 4; ++mi) {
#pragma unroll
      for (int j = 0; j < 4; ++j) {
        const int m = bm + wm + mi * 16 + lg * 4 + j;
        const float val = (acc[mi][ni][j] + bv) * scale;
        if constexpr (OUT_MODE == 1) {
          unsigned short* out = (unsigned short*)outp;
          out[((size_t)(n >> 6) * M + m) * DHEAD + (n & 63)] = f2bf(val);
        } else if constexpr (OUT_MODE == 2) {
          unsigned short* out = (unsigned short*)outp;
          out[((size_t)(n >> 6) * DHEAD + (n & 63)) * M + m] = f2bf(val);
        } else {
          float* out = (float*)outp;
          out[(size_t)m * N + n] = val;
        }
      }
    }
  }
}

// Q pre-scale folds 1/sqrt(1024) AND log2(e) so attn uses raw exp2.
#define QSCALE 0.04508422f

__global__ __launch_bounds__(256) void proj_qkv_b16(
    const unsigned short* __restrict__ qb, const unsigned short* __restrict__ kb,
    const unsigned short* __restrict__ vb,
    const unsigned short* __restrict__ wqb, const float* __restrict__ bq,
    const unsigned short* __restrict__ wkb, const float* __restrict__ bk,
    const unsigned short* __restrict__ wvb, const float* __restrict__ bv,
    unsigned short* __restrict__ ws) {
  const int z = blockIdx.z;
  if (z == 0)      gemm_body<1, 1, 1>(qb, wqb, bq, ws, QSCALE);
  else if (z == 1) gemm_body<1, 1, 1>(kb, wkb, bk, ws + (size_t)S_LEN * DMODEL, 1.0f);
  else             gemm_body<1, 1, 2>(vb, wvb, bv, ws + (size_t)2 * S_LEN * DMODEL, 1.0f);
}
__global__ __launch_bounds__(256) void outproj_b16(
    const unsigned short* __restrict__ concat, const unsigned short* __restrict__ wob,
    const float* __restrict__ bo, float* __restrict__ out) {
  gemm_body<1, 1, 0>(concat, wob, bo, out, 1.0f);
}
__global__ __launch_bounds__(256) void proj_qkv_f32(
    const float* __restrict__ q, const float* __restrict__ k, const float* __restrict__ v,
    const float* __restrict__ wq, const float* __restrict__ bq,
    const float* __restrict__ wk, const float* __restrict__ bk,
    const float* __restrict__ wv, const float* __restrict__ bv,
    unsigned short* __restrict__ ws) {
  const int z = blockIdx.z;
  if (z == 0)      gemm_body<0, 0, 1>(q, wq, bq, ws, QSCALE);
  else if (z == 1) gemm_body<0, 0, 1>(k, wk, bk, ws + (size_t)S_LEN * DMODEL, 1.0f);
  else             gemm_body<0, 0, 2>(v, wv, bv, ws + (size_t)2 * S_LEN * DMODEL, 1.0f);
}
__global__ __launch_bounds__(256) void outproj_f32(
    const unsigned short* __restrict__ concat, const float* __restrict__ wo,
    const float* __restrict__ bo, float* __restrict__ out) {
  gemm_body<1, 0, 0>(concat, wo, bo, out, 1.0f);
}

// ---------------------------------------------------------------------------
// Flash attention v5.2: r11 structure + vf reads HOISTED above the P
// roundtrip (they depend only on Vlds[buf], not P; the sched_barrier(0)
// otherwise pins them after it — their LDS latency then sits on the
// critical path between P-read and PV-MFMA every tile).
// ---------------------------------------------------------------------------
template<int NSPLIT>
__global__ __launch_bounds__(512, 4) void attn_fwd(
    const unsigned short* __restrict__ Qh, const unsigned short* __restrict__ Kh,
    const unsigned short* __restrict__ Vt, const unsigned long long* __restrict__ lmask,
    unsigned short* __restrict__ outp,   // NSPLIT==1: concat ; NSPLIT==2: opart
    float* __restrict__ lpart) {
  __shared__ unsigned short Klds[2][64 * 64];
  __shared__ unsigned short Vlds[2][64 * 64];
  __shared__ unsigned short P_lds[8][32][76];

  const int tid = threadIdx.x;
  const int l = tid & 63, wid = tid >> 6;
  const int lr = l & 15, lg = l >> 4;
  const int per = 32 * NSPLIT;
  const int swz = (blockIdx.x & 7) * per + (blockIdx.x >> 3);
  const int h = swz / (16 * NSPLIT);
  const int split = (NSPLIT == 2) ? ((swz >> 4) & 1) : 0;
  const int qb = swz & 15;
  const int qrow0 = qb * 256 + wid * 32;
  const int kv0 = split * (S_LEN / NSPLIT);
  constexpr int NT = (S_LEN / NSPLIT) / 64;
  const int T0 = kv0 >> 6;

  const unsigned short* Qbase = Qh + ((size_t)h * S_LEN + qrow0) * DHEAD;
  s16x8 qf[2][2];
#pragma unroll
  for (int sub = 0; sub < 2; ++sub)
#pragma unroll
    for (int ds = 0; ds < 2; ++ds)
      qf[sub][ds] = *(const s16x8*)(Qbase + (sub * 16 + lr) * DHEAD + ds * 32 + lg * 8);

  const int wid_u = __builtin_amdgcn_readfirstlane(wid);
  const int qg0 = qb * 16 + wid_u * 2;
  const unsigned long long* mq0 = lmask + (size_t)qg0 * 64 * 16;
  const unsigned long long* mq1 = mq0 + (size_t)64 * 16;

  const int srow = l >> 3;
  const int schunk = (l & 7) ^ srow;
  const unsigned short* Kst = Kh + (size_t)h * S_LEN * DHEAD
                              + (size_t)(kv0 + wid * 8 + srow) * DHEAD + schunk * 8;
  const unsigned short* Vst = Vt + (size_t)h * DHEAD * S_LEN
                              + (size_t)(wid * 8 + srow) * S_LEN + kv0 + schunk * 8;
  const int sdst = (wid * 8) * 64;

  f32x4 o_acc[2][4] = {};
  float lsum[2] = {0.f, 0.f};

  gload_lds16(Kst, &Klds[0][sdst]);
  gload_lds16(Vst, &Vlds[0][sdst]);
  __syncthreads();

  const int xr = lr & 7;

  for (int t = 0; t < NT; ++t) {
    const int buf = t & 1;
    if (t < NT - 1) {
      gload_lds16(Kst + (size_t)(t + 1) * 64 * DHEAD, &Klds[buf ^ 1][sdst]);
      gload_lds16(Vst + (t + 1) * 64, &Vlds[buf ^ 1][sdst]);
    }

    const unsigned short* Kb = &Klds[buf][0];
    f32x4 sc[2][4];
    __builtin_amdgcn_s_setprio(1);
#pragma unroll
    for (int kg = 0; kg < 4; ++kg) {
      const int r = kg * 16 + lr;
      s16x8 k0 = *(const s16x8*)(Kb + r * 64 + ((lg ^ xr) * 8));
      s16x8 k1 = *(const s16x8*)(Kb + r * 64 + (((lg + 4) ^ xr) * 8));
#pragma unroll
      for (int sub = 0; sub < 2; ++sub) {
        f32x4 z = {};
        z = __builtin_amdgcn_mfma_f32_16x16x32_bf16(k0, qf[sub][0], z, 0, 0, 0);
        sc[sub][kg] = __builtin_amdgcn_mfma_f32_16x16x32_bf16(k1, qf[sub][1], z, 0, 0, 0);
      }
    }
    __builtin_amdgcn_s_setprio(0);

    // ---- hoisted V-fragment reads: issue now, complete under softmax VALU ----
    const unsigned short* Vb = &Vlds[buf][0];
    s16x8 vf[4][2];
#pragma unroll
    for (int dg = 0; dg < 4; ++dg) {
      const int r = dg * 16 + lr;
      vf[dg][0] = *(const s16x8*)(Vb + r * 64 + ((lg ^ xr) * 8));
      vf[dg][1] = *(const s16x8*)(Vb + r * 64 + (((lg + 4) ^ xr) * 8));
    }

    const size_t mo = (size_t)(T0 + t) * 16;
#pragma unroll
    for (int sub = 0; sub < 2; ++sub) {
      const unsigned long long* qp = (sub ? mq1 : mq0) + mo;
#pragma unroll
      for (int kg = 0; kg < 4; ++kg) {
        float p[4];
#pragma unroll
        for (int j = 0; j < 4; ++j) {
          const unsigned long long mw = qp[kg * 4 + j];
          float pv = fexp2(sc[sub][kg][j]);
          asm("v_cndmask_b32 %0, %1, 0, %2" : "=v"(pv) : "v"(pv), "s"(mw));
          p[j] = pv;
          lsum[sub] += pv;
        }
        unsigned int w0, w1;
        asm("v_cvt_pk_bf16_f32 %0, %1, %2" : "=v"(w0) : "v"(p[0]), "v"(p[1]));
        asm("v_cvt_pk_bf16_f32 %0, %1, %2" : "=v"(w1) : "v"(p[2]), "v"(p[3]));
        uint2 pk; pk.x = w0; pk.y = w1;
        *(uint2*)&P_lds[wid][sub * 16 + lr][kg * 16 + lg * 4] = pk;
      }
    }
    asm volatile("s_waitcnt lgkmcnt(0)" ::: "memory");
    __builtin_amdgcn_sched_barrier(0);

    s16x8 pf[2][2];
#pragma unroll
    for (int sub = 0; sub < 2; ++sub)
#pragma unroll
      for (int ks = 0; ks < 2; ++ks)
        pf[sub][ks] = *(const s16x8*)&P_lds[wid][sub * 16 + lr][ks * 32 + lg * 8];

    __builtin_amdgcn_s_setprio(1);
#pragma unroll
    for (int dg = 0; dg < 4; ++dg) {
#pragma unroll
      for (int sub = 0; sub < 2; ++sub) {
        o_acc[sub][dg] = __builtin_amdgcn_mfma_f32_16x16x32_bf16(pf[sub][0], vf[dg][0], o_acc[sub][dg], 0, 0, 0);
        o_acc[sub][dg] = __builtin_amdgcn_mfma_f32_16x16x32_bf16(pf[sub][1], vf[dg][1], o_acc[sub][dg], 0, 0, 0);
      }
    }
    __builtin_amdgcn_s_setprio(0);

    __syncthreads();
  }

#pragma unroll
  for (int sub = 0; sub < 2; ++sub) {
    lsum[sub] += __shfl_xor(lsum[sub], 16, 64);
    lsum[sub] += __shfl_xor(lsum[sub], 32, 64);
  }

  if constexpr (NSPLIT == 2) {
    unsigned short* op = outp + ((size_t)(split * NHEADS + h) * S_LEN) * DHEAD;
#pragma unroll
    for (int sub = 0; sub < 2; ++sub)
#pragma unroll
      for (int dg = 0; dg < 4; ++dg)
#pragma unroll
        for (int j = 0; j < 4; ++j) {
          const int q = qrow0 + sub * 16 + lg * 4 + j;
          op[(size_t)q * DHEAD + dg * 16 + lr] = f2bf(o_acc[sub][dg][j]);
        }
    if (l < 16) {
      float* lp = lpart + (size_t)(split * NHEADS + h) * S_LEN + qrow0;
      lp[lr] = lsum[0];
      lp[16 + lr] = lsum[1];
    }
  } else {
    float rs[2][4];
#pragma unroll
    for (int sub = 0; sub < 2; ++sub)
#pragma unroll
      for (int j = 0; j < 4; ++j)
        rs[sub][j] = __shfl(lsum[sub], lg * 4 + j, 64);
#pragma unroll
    for (int sub = 0; sub < 2; ++sub)
#pragma unroll
      for (int dg = 0; dg < 4; ++dg)
#pragma unroll
        for (int j = 0; j < 4; ++j) {
          const int q = qrow0 + sub * 16 + lg * 4 + j;
          outp[(size_t)q * DMODEL + h * DHEAD + dg * 16 + lr] =
              f2bf(o_acc[sub][dg][j] / rs[sub][j]);
        }
  }
}

// ---------------------------------------------------------------------------
// combine: concat = (o0 + o1) / (l0 + l1)
// ---------------------------------------------------------------------------
__global__ __launch_bounds__(256) void attn_combine(
    const unsigned short* __restrict__ opart, const float* __restrict__ lpart,
    unsigned short* __restrict__ concat) {
  const int idx = blockIdx.x * 256 + threadIdx.x;
  const int d4 = (idx & 15) * 4;
  const int hq = idx >> 4;
  const int h = hq >> 12, q = hq & 4095;
  const size_t o0 = ((size_t)h * S_LEN + q) * DHEAD + d4;
  const size_t o1 = o0 + (size_t)NHEADS * S_LEN * DHEAD;
  const float linv = 1.0f / (lpart[(size_t)h * S_LEN + q] +
                             lpart[(size_t)(NHEADS + h) * S_LEN + q]);
  s16x4 a = *(const s16x4*)(opart + o0);
  s16x4 b = *(const s16x4*)(opart + o1);
  s16x4 r;
#pragma unroll
  for (int i = 0; i < 4; ++i) {
    union { unsigned int u; float f; } xa, xb;
    xa.u = ((unsigned int)(unsigned short)a[i]) << 16;
    xb.u = ((unsigned int)(unsigned short)b[i]) << 16;
    r[i] = (short)f2bf((xa.f + xb.f) * linv);
  }
  *(s16x4*)(concat + ((size_t)q * DMODEL + h * DHEAD + d4)) = r;
}

// ---------------------------------------------------------------------------
extern "C" void kernel_launch(void* const* d_in, const int* in_sizes, int n_in,
                              void* d_out, int out_size, void* d_ws, size_t ws_size,
                              hipStream_t stream) {
  const float* q  = (const float*)d_in[0];
  const float* k  = (const float*)d_in[1];
  const float* v  = (const float*)d_in[2];
  const int* mask = (const int*)d_in[3];
  const float* wq = (const float*)d_in[4];
  const float* bq = (const float*)d_in[5];
  const float* wk = (const float*)d_in[6];
  const float* bk = (const float*)d_in[7];
  const float* wv = (const float*)d_in[8];
  const float* bv = (const float*)d_in[9];
  const float* wo = (const float*)d_in[10];
  const float* bo = (const float*)d_in[11];
  float* out = (float*)d_out;

  const size_t SD = (size_t)S_LEN * DMODEL, DD = (size_t)DMODEL * DMODEL;
  // base: Qh | Kh | Vt | concat | lmask(2MB) | bits(2MB)
  unsigned short* wsq = (unsigned short*)d_ws;
  unsigned short* wsc = wsq + 3 * SD;
  unsigned long long* wslm = (unsigned long long*)(wsc + SD);
  unsigned long long* wsbits = wslm + (size_t)256 * 64 * 16;
  // cast region (big path): qb kb vb | wqb wkb wvb wob ; opart/lpart alias qb..vb
  unsigned short* cast0 = (unsigned short*)(wsbits + (size_t)S_LEN * 64);
  const size_t need = (size_t)((char*)(cast0 + 3 * SD + 4 * DD) - (char*)d_ws);
  const bool big = ws_size >= need;

  if (big) {
    unsigned short* qb  = cast0;
    unsigned short* kb  = qb + SD;
    unsigned short* vb  = kb + SD;
    unsigned short* wqb = vb + SD;
    unsigned short* wkb = wqb + DD;
    unsigned short* wvb = wkb + DD;
    unsigned short* wob = wvb + DD;
    unsigned short* opart = cast0;               // 16MB = qb+kb (dead after proj)
    float* lpart = (float*)vb;                   // 512KB (dead after proj)
    prep_fused<<<dim3(4096, 8), dim3(256), 0, stream>>>(q, k, v, wq, wk, wv, wo,
                                                        cast0, mask, wsbits);
    mask_xpose<<<dim3(4096), dim3(256), 0, stream>>>(wsbits, wslm);
    proj_qkv_b16<<<dim3(32, 8, 3), dim3(256), 0, stream>>>(qb, kb, vb, wqb, bq, wkb, bk, wvb, bv, wsq);
    attn_fwd<2><<<dim3(512), dim3(512), 0, stream>>>(wsq, wsq + SD, wsq + 2 * SD, wslm, opart, lpart);
    attn_combine<<<dim3(4096), dim3(256), 0, stream>>>(opart, lpart, wsc);
    outproj_b16<<<dim3(32, 8), dim3(256), 0, stream>>>(wsc, wob, bo, out);
  } else {
    mask_pack<<<dim3(S_LEN), dim3(256), 0, stream>>>(mask, wsbits);
    mask_xpose<<<dim3(4096), dim3(256), 0, stream>>>(wsbits, wslm);
    proj_qkv_f32<<<dim3(32, 8, 3), dim3(256), 0, stream>>>(q, k, v, wq, bq, wk, bk, wv, bv, wsq);
    attn_fwd<1><<<dim3(256), dim3(512), 0, stream>>>(wsq, wsq + SD, wsq + 2 * SD, wslm, wsc, nullptr);
    outproj_f32<<<dim3(32, 8), dim3(256), 0, stream>>>(wsc, wo, bo, out);
  }
}

// Round 16
// 195.492 us; speedup vs baseline: 1.3205x; 1.3205x over previous
//
#include <hip/hip_runtime.h>
#include <hip/hip_bf16.h>
#include <math.h>

typedef __attribute__((ext_vector_type(4))) float f32x4;
typedef __attribute__((ext_vector_type(8))) short s16x8;
typedef __attribute__((ext_vector_type(4))) short s16x4;

#define S_LEN 4096
#define DMODEL 1024
#define NHEADS 16
#define DHEAD 64

__device__ __forceinline__ unsigned short f2bf(float f) {
  union { float f; unsigned int u; } x; x.f = f;
  return (unsigned short)((x.u + 0x7FFFu + ((x.u >> 16) & 1u)) >> 16);
}

__device__ __forceinline__ float fexp2(float x) {
#if __has_builtin(__builtin_amdgcn_exp2f)
  return __builtin_amdgcn_exp2f(x);
#else
  float r; asm("v_exp_f32 %0, %1" : "=v"(r) : "v"(x)); return r;
#endif
}

__device__ __forceinline__ void gload_lds16(const void* g, void* l) {
  __builtin_amdgcn_global_load_lds(
      (const __attribute__((address_space(1))) unsigned int*)g,
      (__attribute__((address_space(3))) unsigned int*)l, 16, 0, 0);
}

// ---------------------------------------------------------------------------
// mask pre-pass 1 body (r7-exact, COALESCED 64MB read): int32 mask [S][S] ->
// bits[qr][t] u64 (bit l = key t*64+l).
// ---------------------------------------------------------------------------
__device__ __forceinline__ void mask_pack_body(const int* __restrict__ mask,
                                               unsigned long long* __restrict__ bits,
                                               int qr) {
  const int wv = threadIdx.x >> 6, l = threadIdx.x & 63;
  const int* row = mask + (size_t)qr * S_LEN;
#pragma unroll
  for (int w0 = 0; w0 < 64; w0 += 4) {
    const int w = w0 + wv;
    unsigned long long b = __ballot(row[w * 64 + l] != 0);
    if (l == 0) bits[(size_t)qr * 64 + w] = b;
  }
}

__global__ __launch_bounds__(256) void mask_pack(const int* __restrict__ mask,
                                                 unsigned long long* __restrict__ bits) {
  mask_pack_body(mask, bits, blockIdx.x);
}

// ---------------------------------------------------------------------------
// mask pre-pass 2 (r7-exact, transpose on the 2MB bits array):
// lmask[qg][t][w], w=kg*4+j: bit[lane] = mask[qg*16+(lane&15)]
//                                             [t*64+kg*16+(lane>>4)*4+j]
// ---------------------------------------------------------------------------
__global__ __launch_bounds__(256) void mask_xpose(const unsigned long long* __restrict__ bits,
                                                  unsigned long long* __restrict__ lmask) {
  const int wv = blockIdx.x * 4 + (threadIdx.x >> 6);
  const int l = threadIdx.x & 63, lr = l & 15, lg4 = (l >> 4) * 4;
  const int qg = wv >> 6, t = wv & 63;
  const unsigned long long rw = bits[(size_t)(qg * 16 + lr) * 64 + t];
  unsigned long long mine = 0;
#pragma unroll
  for (int w = 0; w < 16; ++w) {
    const int sh = (w >> 2) * 16 + (w & 3) + lg4;
    unsigned long long b = __ballot(((rw >> sh) & 1ull) != 0);
    if (l == w) mine = b;
  }
  if (l < 16) lmask[((size_t)qg * 64 + t) * 16 + l] = mine;
}

// ---------------------------------------------------------------------------
// fused prep (big path, r14-exact): planes y<7 = fp32->bf16 cast,
// plane y==7 = COALESCED mask_pack (qr = blockIdx.x).
// ---------------------------------------------------------------------------
__global__ __launch_bounds__(256) void prep_fused(
    const float* __restrict__ s0, const float* __restrict__ s1, const float* __restrict__ s2,
    const float* __restrict__ s3, const float* __restrict__ s4, const float* __restrict__ s5,
    const float* __restrict__ s6, unsigned short* __restrict__ dst,
    const int* __restrict__ mask, unsigned long long* __restrict__ bits) {
  const int z = blockIdx.y;
  if (z == 7) {
    mask_pack_body(mask, bits, blockIdx.x);
    return;
  }
  const float* src = (z == 0) ? s0 : (z == 1) ? s1 : (z == 2) ? s2 :
                     (z == 3) ? s3 : (z == 4) ? s4 : (z == 5) ? s5 : s6;
  const int n = (z < 3) ? (S_LEN * DMODEL) : (DMODEL * DMODEL);
  unsigned short* d = dst + ((z < 3) ? (size_t)z * S_LEN * DMODEL
                                     : (size_t)3 * S_LEN * DMODEL + (size_t)(z - 3) * DMODEL * DMODEL);
  const int i = (blockIdx.x * 256 + threadIdx.x) * 4;
  if (i < n) {
    f32x4 v = *(const f32x4*)(src + i);
    s16x4 o;
#pragma unroll
    for (int j = 0; j < 4; ++j) o[j] = (short)f2bf(v[j]);
    *(s16x4*)(d + i) = o;
  }
}

// ---------------------------------------------------------------------------
// GEMM body (r7-exact, reg-staged, LDT=40 — measured-best: compiler hoists
// next-tile global loads above the barrier = implicit pipelining).
// ---------------------------------------------------------------------------
template<int A_BF16, int B_BF16, int OUT_MODE>
__device__ __forceinline__ void gemm_body(const void* __restrict__ Ap,
                                          const void* __restrict__ Wp,
                                          const float* __restrict__ bias,
                                          void* __restrict__ outp, float scale) {
  constexpr int K = DMODEL, N = DMODEL, M = S_LEN;
  constexpr int BM = 128, BK = 32, LDT = 40;
  __shared__ unsigned short Alds[BM * LDT];
  __shared__ unsigned short Blds[BM * LDT];
  const int tid = threadIdx.x;
  const int l = tid & 63, wid = tid >> 6;
  const int lr = l & 15, lg = l >> 4;
  const int bm = blockIdx.x * BM;
  const int bn = blockIdx.y * BM;
  const int wm = (wid >> 1) * 64, wn = (wid & 1) * 64;

  f32x4 acc[4][4] = {};

  for (int k0 = 0; k0 < K; k0 += BK) {
    __syncthreads();
    if constexpr (A_BF16) {
      const unsigned short* A = (const unsigned short*)Ap;
      const int col = (tid & 3) * 8, row = tid >> 2;
#pragma unroll
      for (int p = 0; p < 2; ++p) {
        const int r = row + p * 64;
        *(s16x8*)&Alds[r * LDT + col] =
            *(const s16x8*)(A + (size_t)(bm + r) * K + k0 + col);
      }
    } else {
      const float* A = (const float*)Ap;
      const int col = (tid & 7) * 4, row = tid >> 3;
#pragma unroll
      for (int p = 0; p < 4; ++p) {
        const int r = row + p * 32;
        f32x4 vv = *(const f32x4*)(A + (size_t)(bm + r) * K + k0 + col);
        s16x4 o;
#pragma unroll
        for (int j = 0; j < 4; ++j) o[j] = (short)f2bf(vv[j]);
        *(s16x4*)&Alds[r * LDT + col] = o;
      }
    }
    if constexpr (B_BF16) {
      const unsigned short* W = (const unsigned short*)Wp;
      const int col = (tid & 3) * 8, row = tid >> 2;
#pragma unroll
      for (int p = 0; p < 2; ++p) {
        const int r = row + p * 64;
        *(s16x8*)&Blds[r * LDT + col] =
            *(const s16x8*)(W + (size_t)(bn + r) * K + k0 + col);
      }
    } else {
      const float* W = (const float*)Wp;
      const int col = (tid & 7) * 4, row = tid >> 3;
#pragma unroll
      for (int p = 0; p < 4; ++p) {
        const int r = row + p * 32;
        f32x4 vv = *(const f32x4*)(W + (size_t)(bn + r) * K + k0 + col);
        s16x4 o;
#pragma unroll
        for (int j = 0; j < 4; ++j) o[j] = (short)f2bf(vv[j]);
        *(s16x4*)&Blds[r * LDT + col] = o;
      }
    }
    __syncthreads();
    s16x8 af[4], bfr[4];
#pragma unroll
    for (int mi = 0; mi < 4; ++mi)
      af[mi] = *(const s16x8*)&Alds[(wm + mi * 16 + lr) * LDT + lg * 8];
#pragma unroll
    for (int ni = 0; ni < 4; ++ni)
      bfr[ni] = *(const s16x8*)&Blds[(wn + ni * 16 + lr) * LDT + lg * 8];
#pragma unroll
    for (int mi = 0; mi < 4; ++mi)
#pragma unroll
      for (int ni = 0; ni < 4; ++ni)
        acc[mi][ni] = __builtin_amdgcn_mfma_f32_16x16x32_bf16(af[mi], bfr[ni], acc[mi][ni], 0, 0, 0);
  }

#pragma unroll
  for (int ni = 0; ni < 4; ++ni) {
    const int n = bn + wn + ni * 16 + lr;
    const float bv = bias[n];
#pragma unroll
    for (int mi = 0; mi < 4; ++mi) {
#pragma unroll
      for (int j = 0; j < 4; ++j) {
        const int m = bm + wm + mi * 16 + lg * 4 + j;
        const float val = (acc[mi][ni][j] + bv) * scale;
        if constexpr (OUT_MODE == 1) {
          unsigned short* out = (unsigned short*)outp;
          out[((size_t)(n >> 6) * M + m) * DHEAD + (n & 63)] = f2bf(val);
        } else if constexpr (OUT_MODE == 2) {
          unsigned short* out = (unsigned short*)outp;
          out[((size_t)(n >> 6) * DHEAD + (n & 63)) * M + m] = f2bf(val);
        } else {
          float* out = (float*)outp;
          out[(size_t)m * N + n] = val;
        }
      }
    }
  }
}

// Q pre-scale folds 1/sqrt(1024) AND log2(e) so attn uses raw exp2.
#define QSCALE 0.04508422f

__global__ __launch_bounds__(256) void proj_qkv_b16(
    const unsigned short* __restrict__ qb, const unsigned short* __restrict__ kb,
    const unsigned short* __restrict__ vb,
    const unsigned short* __restrict__ wqb, const float* __restrict__ bq,
    const unsigned short* __restrict__ wkb, const float* __restrict__ bk,
    const unsigned short* __restrict__ wvb, const float* __restrict__ bv,
    unsigned short* __restrict__ ws) {
  const int z = blockIdx.z;
  if (z == 0)      gemm_body<1, 1, 1>(qb, wqb, bq, ws, QSCALE);
  else if (z == 1) gemm_body<1, 1, 1>(kb, wkb, bk, ws + (size_t)S_LEN * DMODEL, 1.0f);
  else             gemm_body<1, 1, 2>(vb, wvb, bv, ws + (size_t)2 * S_LEN * DMODEL, 1.0f);
}
__global__ __launch_bounds__(256) void outproj_b16(
    const unsigned short* __restrict__ concat, const unsigned short* __restrict__ wob,
    const float* __restrict__ bo, float* __restrict__ out) {
  gemm_body<1, 1, 0>(concat, wob, bo, out, 1.0f);
}
__global__ __launch_bounds__(256) void proj_qkv_f32(
    const float* __restrict__ q, const float* __restrict__ k, const float* __restrict__ v,
    const float* __restrict__ wq, const float* __restrict__ bq,
    const float* __restrict__ wk, const float* __restrict__ bk,
    const float* __restrict__ wv, const float* __restrict__ bv,
    unsigned short* __restrict__ ws) {
  const int z = blockIdx.z;
  if (z == 0)      gemm_body<0, 0, 1>(q, wq, bq, ws, QSCALE);
  else if (z == 1) gemm_body<0, 0, 1>(k, wk, bk, ws + (size_t)S_LEN * DMODEL, 1.0f);
  else             gemm_body<0, 0, 2>(v, wv, bv, ws + (size_t)2 * S_LEN * DMODEL, 1.0f);
}
__global__ __launch_bounds__(256) void outproj_f32(
    const unsigned short* __restrict__ concat, const float* __restrict__ wo,
    const float* __restrict__ bo, float* __restrict__ out) {
  gemm_body<1, 0, 0>(concat, wo, bo, out, 1.0f);
}

// ---------------------------------------------------------------------------
// Flash attention v5.1 (r11/r14-exact — conflicts 0, near LDS floor):
// 8 waves x 32 q-rows, split-K partials, fixed-max exp2, SGPR mask words,
// P_lds pad 76. NOTE (r15 lesson): do NOT hoist vf reads above the
// sched_barrier(0) fence — holding them live across it exceeds the
// launch_bounds(512,4) VGPR cap and the compiler spills to scratch
// (WRITE_SIZE 17KB -> 192MB, attn 92 -> 157us).
// ---------------------------------------------------------------------------
template<int NSPLIT>
__global__ __launch_bounds__(512, 4) void attn_fwd(
    const unsigned short* __restrict__ Qh, const unsigned short* __restrict__ Kh,
    const unsigned short* __restrict__ Vt, const unsigned long long* __restrict__ lmask,
    unsigned short* __restrict__ outp,   // NSPLIT==1: concat ; NSPLIT==2: opart
    float* __restrict__ lpart) {
  __shared__ unsigned short Klds[2][64 * 64];
  __shared__ unsigned short Vlds[2][64 * 64];
  __shared__ unsigned short P_lds[8][32][76];

  const int tid = threadIdx.x;
  const int l = tid & 63, wid = tid >> 6;
  const int lr = l & 15, lg = l >> 4;
  const int per = 32 * NSPLIT;
  const int swz = (blockIdx.x & 7) * per + (blockIdx.x >> 3);
  const int h = swz / (16 * NSPLIT);
  const int split = (NSPLIT == 2) ? ((swz >> 4) & 1) : 0;
  const int qb = swz & 15;
  const int qrow0 = qb * 256 + wid * 32;
  const int kv0 = split * (S_LEN / NSPLIT);
  constexpr int NT = (S_LEN / NSPLIT) / 64;
  const int T0 = kv0 >> 6;

  const unsigned short* Qbase = Qh + ((size_t)h * S_LEN + qrow0) * DHEAD;
  s16x8 qf[2][2];
#pragma unroll
  for (int sub = 0; sub < 2; ++sub)
#pragma unroll
    for (int ds = 0; ds < 2; ++ds)
      qf[sub][ds] = *(const s16x8*)(Qbase + (sub * 16 + lr) * DHEAD + ds * 32 + lg * 8);

  const int wid_u = __builtin_amdgcn_readfirstlane(wid);
  const int qg0 = qb * 16 + wid_u * 2;
  const unsigned long long* mq0 = lmask + (size_t)qg0 * 64 * 16;
  const unsigned long long* mq1 = mq0 + (size_t)64 * 16;

  const int srow = l >> 3;
  const int schunk = (l & 7) ^ srow;
  const unsigned short* Kst = Kh + (size_t)h * S_LEN * DHEAD
                              + (size_t)(kv0 + wid * 8 + srow) * DHEAD + schunk * 8;
  const unsigned short* Vst = Vt + (size_t)h * DHEAD * S_LEN
                              + (size_t)(wid * 8 + srow) * S_LEN + kv0 + schunk * 8;
  const int sdst = (wid * 8) * 64;

  f32x4 o_acc[2][4] = {};
  float lsum[2] = {0.f, 0.f};

  gload_lds16(Kst, &Klds[0][sdst]);
  gload_lds16(Vst, &Vlds[0][sdst]);
  __syncthreads();

  const int xr = lr & 7;

  for (int t = 0; t < NT; ++t) {
    const int buf = t & 1;
    if (t < NT - 1) {
      gload_lds16(Kst + (size_t)(t + 1) * 64 * DHEAD, &Klds[buf ^ 1][sdst]);
      gload_lds16(Vst + (t + 1) * 64, &Vlds[buf ^ 1][sdst]);
    }

    const unsigned short* Kb = &Klds[buf][0];
    f32x4 sc[2][4];
    __builtin_amdgcn_s_setprio(1);
#pragma unroll
    for (int kg = 0; kg < 4; ++kg) {
      const int r = kg * 16 + lr;
      s16x8 k0 = *(const s16x8*)(Kb + r * 64 + ((lg ^ xr) * 8));
      s16x8 k1 = *(const s16x8*)(Kb + r * 64 + (((lg + 4) ^ xr) * 8));
#pragma unroll
      for (int sub = 0; sub < 2; ++sub) {
        f32x4 z = {};
        z = __builtin_amdgcn_mfma_f32_16x16x32_bf16(k0, qf[sub][0], z, 0, 0, 0);
        sc[sub][kg] = __builtin_amdgcn_mfma_f32_16x16x32_bf16(k1, qf[sub][1], z, 0, 0, 0);
      }
    }
    __builtin_amdgcn_s_setprio(0);

    const size_t mo = (size_t)(T0 + t) * 16;
#pragma unroll
    for (int sub = 0; sub < 2; ++sub) {
      const unsigned long long* qp = (sub ? mq1 : mq0) + mo;
#pragma unroll
      for (int kg = 0; kg < 4; ++kg) {
        float p[4];
#pragma unroll
        for (int j = 0; j < 4; ++j) {
          const unsigned long long mw = qp[kg * 4 + j];
          float pv = fexp2(sc[sub][kg][j]);
          asm("v_cndmask_b32 %0, %1, 0, %2" : "=v"(pv) : "v"(pv), "s"(mw));
          p[j] = pv;
          lsum[sub] += pv;
        }
        unsigned int w0, w1;
        asm("v_cvt_pk_bf16_f32 %0, %1, %2" : "=v"(w0) : "v"(p[0]), "v"(p[1]));
        asm("v_cvt_pk_bf16_f32 %0, %1, %2" : "=v"(w1) : "v"(p[2]), "v"(p[3]));
        uint2 pk; pk.x = w0; pk.y = w1;
        *(uint2*)&P_lds[wid][sub * 16 + lr][kg * 16 + lg * 4] = pk;
      }
    }
    asm volatile("s_waitcnt lgkmcnt(0)" ::: "memory");
    __builtin_amdgcn_sched_barrier(0);

    s16x8 pf[2][2];
#pragma unroll
    for (int sub = 0; sub < 2; ++sub)
#pragma unroll
      for (int ks = 0; ks < 2; ++ks)
        pf[sub][ks] = *(const s16x8*)&P_lds[wid][sub * 16 + lr][ks * 32 + lg * 8];

    const unsigned short* Vb = &Vlds[buf][0];
    __builtin_amdgcn_s_setprio(1);
#pragma unroll
    for (int dg = 0; dg < 4; ++dg) {
      const int r = dg * 16 + lr;
      s16x8 v0 = *(const s16x8*)(Vb + r * 64 + ((lg ^ xr) * 8));
      s16x8 v1 = *(const s16x8*)(Vb + r * 64 + (((lg + 4) ^ xr) * 8));
#pragma unroll
      for (int sub = 0; sub < 2; ++sub) {
        o_acc[sub][dg] = __builtin_amdgcn_mfma_f32_16x16x32_bf16(pf[sub][0], v0, o_acc[sub][dg], 0, 0, 0);
        o_acc[sub][dg] = __builtin_amdgcn_mfma_f32_16x16x32_bf16(pf[sub][1], v1, o_acc[sub][dg], 0, 0, 0);
      }
    }
    __builtin_amdgcn_s_setprio(0);

    __syncthreads();
  }

#pragma unroll
  for (int sub = 0; sub < 2; ++sub) {
    lsum[sub] += __shfl_xor(lsum[sub], 16, 64);
    lsum[sub] += __shfl_xor(lsum[sub], 32, 64);
  }

  if constexpr (NSPLIT == 2) {
    unsigned short* op = outp + ((size_t)(split * NHEADS + h) * S_LEN) * DHEAD;
#pragma unroll
    for (int sub = 0; sub < 2; ++sub)
#pragma unroll
      for (int dg = 0; dg < 4; ++dg)
#pragma unroll
        for (int j = 0; j < 4; ++j) {
          const int q = qrow0 + sub * 16 + lg * 4 + j;
          op[(size_t)q * DHEAD + dg * 16 + lr] = f2bf(o_acc[sub][dg][j]);
        }
    if (l < 16) {
      float* lp = lpart + (size_t)(split * NHEADS + h) * S_LEN + qrow0;
      lp[lr] = lsum[0];
      lp[16 + lr] = lsum[1];
    }
  } else {
    float rs[2][4];
#pragma unroll
    for (int sub = 0; sub < 2; ++sub)
#pragma unroll
      for (int j = 0; j < 4; ++j)
        rs[sub][j] = __shfl(lsum[sub], lg * 4 + j, 64);
#pragma unroll
    for (int sub = 0; sub < 2; ++sub)
#pragma unroll
      for (int dg = 0; dg < 4; ++dg)
#pragma unroll
        for (int j = 0; j < 4; ++j) {
          const int q = qrow0 + sub * 16 + lg * 4 + j;
          outp[(size_t)q * DMODEL + h * DHEAD + dg * 16 + lr] =
              f2bf(o_acc[sub][dg][j] / rs[sub][j]);
        }
  }
}

// ---------------------------------------------------------------------------
// combine: concat = (o0 + o1) / (l0 + l1)
// ---------------------------------------------------------------------------
__global__ __launch_bounds__(256) void attn_combine(
    const unsigned short* __restrict__ opart, const float* __restrict__ lpart,
    unsigned short* __restrict__ concat) {
  const int idx = blockIdx.x * 256 + threadIdx.x;
  const int d4 = (idx & 15) * 4;
  const int hq = idx >> 4;
  const int h = hq >> 12, q = hq & 4095;
  const size_t o0 = ((size_t)h * S_LEN + q) * DHEAD + d4;
  const size_t o1 = o0 + (size_t)NHEADS * S_LEN * DHEAD;
  const float linv = 1.0f / (lpart[(size_t)h * S_LEN + q] +
                             lpart[(size_t)(NHEADS + h) * S_LEN + q]);
  s16x4 a = *(const s16x4*)(opart + o0);
  s16x4 b = *(const s16x4*)(opart + o1);
  s16x4 r;
#pragma unroll
  for (int i = 0; i < 4; ++i) {
    union { unsigned int u; float f; } xa, xb;
    xa.u = ((unsigned int)(unsigned short)a[i]) << 16;
    xb.u = ((unsigned int)(unsigned short)b[i]) << 16;
    r[i] = (short)f2bf((xa.f + xb.f) * linv);
  }
  *(s16x4*)(concat + ((size_t)q * DMODEL + h * DHEAD + d4)) = r;
}

// ---------------------------------------------------------------------------
extern "C" void kernel_launch(void* const* d_in, const int* in_sizes, int n_in,
                              void* d_out, int out_size, void* d_ws, size_t ws_size,
                              hipStream_t stream) {
  const float* q  = (const float*)d_in[0];
  const float* k  = (const float*)d_in[1];
  const float* v  = (const float*)d_in[2];
  const int* mask = (const int*)d_in[3];
  const float* wq = (const float*)d_in[4];
  const float* bq = (const float*)d_in[5];
  const float* wk = (const float*)d_in[6];
  const float* bk = (const float*)d_in[7];
  const float* wv = (const float*)d_in[8];
  const float* bv = (const float*)d_in[9];
  const float* wo = (const float*)d_in[10];
  const float* bo = (const float*)d_in[11];
  float* out = (float*)d_out;

  const size_t SD = (size_t)S_LEN * DMODEL, DD = (size_t)DMODEL * DMODEL;
  // base: Qh | Kh | Vt | concat | lmask(2MB) | bits(2MB)
  unsigned short* wsq = (unsigned short*)d_ws;
  unsigned short* wsc = wsq + 3 * SD;
  unsigned long long* wslm = (unsigned long long*)(wsc + SD);
  unsigned long long* wsbits = wslm + (size_t)256 * 64 * 16;
  // cast region (big path): qb kb vb | wqb wkb wvb wob ; opart/lpart alias qb..vb
  unsigned short* cast0 = (unsigned short*)(wsbits + (size_t)S_LEN * 64);
  const size_t need = (size_t)((char*)(cast0 + 3 * SD + 4 * DD) - (char*)d_ws);
  const bool big = ws_size >= need;

  if (big) {
    unsigned short* qb  = cast0;
    unsigned short* kb  = qb + SD;
    unsigned short* vb  = kb + SD;
    unsigned short* wqb = vb + SD;
    unsigned short* wkb = wqb + DD;
    unsigned short* wvb = wkb + DD;
    unsigned short* wob = wvb + DD;
    unsigned short* opart = cast0;               // 16MB = qb+kb (dead after proj)
    float* lpart = (float*)vb;                   // 512KB (dead after proj)
    prep_fused<<<dim3(4096, 8), dim3(256), 0, stream>>>(q, k, v, wq, wk, wv, wo,
                                                        cast0, mask, wsbits);
    mask_xpose<<<dim3(4096), dim3(256), 0, stream>>>(wsbits, wslm);
    proj_qkv_b16<<<dim3(32, 8, 3), dim3(256), 0, stream>>>(qb, kb, vb, wqb, bq, wkb, bk, wvb, bv, wsq);
    attn_fwd<2><<<dim3(512), dim3(512), 0, stream>>>(wsq, wsq + SD, wsq + 2 * SD, wslm, opart, lpart);
    attn_combine<<<dim3(4096), dim3(256), 0, stream>>>(opart, lpart, wsc);
    outproj_b16<<<dim3(32, 8), dim3(256), 0, stream>>>(wsc, wob, bo, out);
  } else {
    mask_pack<<<dim3(S_LEN), dim3(256), 0, stream>>>(mask, wsbits);
    mask_xpose<<<dim3(4096), dim3(256), 0, stream>>>(wsbits, wslm);
    proj_qkv_f32<<<dim3(32, 8, 3), dim3(256), 0, stream>>>(q, k, v, wq, bq, wk, bk, wv, bv, wsq);
    attn_fwd<1><<<dim3(256), dim3(512), 0, stream>>>(wsq, wsq + SD, wsq + 2 * SD, wslm, wsc, nullptr);
    outproj_f32<<<dim3(32, 8), dim3(256), 0, stream>>>(wsc, wo, bo, out);
  }
}